// Round 12
// baseline (124.899 us; speedup 1.0000x reference)
//
#include <hip/hip_runtime.h>

#define N_NODES 50000
#define N_EDGES 600000
#define DIM 128

#define CAP 64                 // bucket capacity per node (deg ~Poisson(12))
#define BLK_ROWS 16
#define GRID_FUSED 3125        // 50000/16 exact

// dummy edge: col=zero-row(50000), a0=5 (bits 60+ of cnt0), a1=3 (bits 30+ of cnt1)
#define DUMMY (50000u | (5u << 16) | (3u << 19))

// ---- ws layout (bytes), 16B-aligned ----
#define WS_CNT_OFF   0          // cnt[50000] int
#define WS_PERM_OFF  200000     // perm[50000*64] u32 = 12.8 MB
#define WS_XB_OFF    13000000   // xb [50001*128] bf16 (row 50000 = zeros)
#define WS_W1B_OFF   25800256   // w1b [256*128] bf16
#define WS_W2B_OFF   25865792   // w2b [128*256] bf16
// total ~25.93 MB

#define CVT_X4    1600000       // 50000*128/4
#define CVT_XROWS 1600032       // + zero row
#define CVT_W4    8192          // 256*128/4
#define CVT_TOTAL (CVT_XROWS + 2 * CVT_W4)
#define CVT_BLOCKS ((CVT_TOTAL + 255) / 256)       // 6315
#define PLACE_BLOCKS ((N_EDGES / 4 + 255) / 256)   // 586, 4 edges/thread
#define PREP_GRID (PLACE_BLOCKS + CVT_BLOCKS)

typedef __attribute__((ext_vector_type(8))) short bf16x8;
typedef __attribute__((ext_vector_type(4))) float f32x4;

__device__ __forceinline__ unsigned short f2bf(float f) {
    unsigned int b = __float_as_uint(f);
    b += 0x7FFFu + ((b >> 16) & 1u);     // round-to-nearest-even
    return (unsigned short)(b >> 16);
}
__device__ __forceinline__ float bf2f(short u) {
    return __uint_as_float(((unsigned int)(unsigned short)u) << 16);
}

// One launch, two independent block ranges (cnt pre-zeroed by hipMemsetAsync):
//   blocks [0, PLACE_BLOCKS): bucket placement, 4 edges/thread
//   blocks [PLACE_BLOCKS, ..): conversions x/W1/W2 -> bf16 (+ zero row)
// Place blocks FIRST so their latency-bound atomics dispatch immediately and
// overlap the streaming cvt blocks.
__global__ __launch_bounds__(256) void prep_kernel(
    const float* __restrict__ x, const float* __restrict__ W1,
    const float* __restrict__ W2, const int* __restrict__ eidx,
    const int* __restrict__ eattr, unsigned short* __restrict__ xb,
    unsigned short* __restrict__ w1b, unsigned short* __restrict__ w2b,
    int* __restrict__ cnt, unsigned int* __restrict__ perm)
{
    if (blockIdx.x < PLACE_BLOCKS) {
        int i = blockIdx.x * 256 + threadIdx.x;
        if (i >= N_EDGES / 4) return;
        int4 rows = reinterpret_cast<const int4*>(eidx)[i];
        int4 cols = reinterpret_cast<const int4*>(eidx + N_EDGES)[i];
        int4 ea01 = reinterpret_cast<const int4*>(eattr)[2 * i];
        int4 ea23 = reinterpret_cast<const int4*>(eattr)[2 * i + 1];
        int r[4] = {rows.x, rows.y, rows.z, rows.w};
        unsigned v[4] = {
            (unsigned)cols.x | ((unsigned)ea01.x << 16) | ((unsigned)ea01.y << 19),
            (unsigned)cols.y | ((unsigned)ea01.z << 16) | ((unsigned)ea01.w << 19),
            (unsigned)cols.z | ((unsigned)ea23.x << 16) | ((unsigned)ea23.y << 19),
            (unsigned)cols.w | ((unsigned)ea23.z << 16) | ((unsigned)ea23.w << 19)};
        #pragma unroll
        for (int q = 0; q < 4; ++q) {
            int pos = atomicAdd(&cnt[r[q]], 1);
            if (pos < CAP)
                perm[(size_t)r[q] * CAP + pos] = v[q];
        }
        return;
    }
    int i = (blockIdx.x - PLACE_BLOCKS) * 256 + threadIdx.x;
    if (i < CVT_X4) {
        float4 v = reinterpret_cast<const float4*>(x)[i];
        reinterpret_cast<ushort4*>(xb)[i] =
            make_ushort4(f2bf(v.x), f2bf(v.y), f2bf(v.z), f2bf(v.w));
    } else if (i < CVT_XROWS) {
        reinterpret_cast<ushort4*>(xb)[i] = make_ushort4(0, 0, 0, 0);
    } else if (i < CVT_XROWS + CVT_W4) {
        int j = i - CVT_XROWS;
        float4 v = reinterpret_cast<const float4*>(W1)[j];
        reinterpret_cast<ushort4*>(w1b)[j] =
            make_ushort4(f2bf(v.x), f2bf(v.y), f2bf(v.z), f2bf(v.w));
    } else if (i < CVT_TOTAL) {
        int j = i - CVT_XROWS - CVT_W4;
        float4 v = reinterpret_cast<const float4*>(W2)[j];
        reinterpret_cast<ushort4*>(w2b)[j] =
            make_ushort4(f2bf(v.x), f2bf(v.y), f2bf(v.z), f2bf(v.w));
    }
}

// Fused: gather 16 node rows into LDS (bf16), then MLP via MFMA.  (== R11, measured 81 µs)
//   agg = xb[g] + Σ_edges xb[col] + Σ_t cnt0[t]·e1[t] + Σ_t cnt1[t]·e2[t]
//   Y   = relu(agg @ W1^T + b1) @ W2^T + b2
// 16x16x32 frag: lane l -> row (l&15), k=(l>>4)*8+j ; D: row=(l>>4)*4+r, col=l&15.
__global__ __launch_bounds__(256, 4) void fused_mlp_kernel(
    const unsigned short* __restrict__ xb,
    const float* __restrict__ e1, const float* __restrict__ e2,
    const unsigned int* __restrict__ perm, const int* __restrict__ cnt,
    const unsigned short* __restrict__ w1b, const float* __restrict__ b1,
    const unsigned short* __restrict__ w2b, const float* __restrict__ b2,
    float* __restrict__ Y)
{
    __shared__ __align__(16) unsigned short sA[16][136];   // 4352 B
    __shared__ __align__(16) unsigned short sH[16][264];   // 8448 B

    int t = threadIdx.x;

    // ---------- gather: 16 lanes per node, 16-deep unconditional batches ----------
    {
        int n  = t >> 4;                      // row within block (grid exact)
        int g  = blockIdx.x * BLK_ROWS + n;
        int ln = t & 15, c0 = ln * 8;

        bf16x8 sx = *reinterpret_cast<const bf16x8*>(xb + (size_t)g * DIM + c0);

        int ne = cnt[g]; if (ne > CAP) ne = CAP;
        const uint4* pp4 = reinterpret_cast<const uint4*>(perm + (size_t)g * CAP);

        unsigned long long c0v = 1ull << 48;  // self-loop a0=4 (12*4)
        unsigned int       c1v = 1u;          // self-loop a1=0
        float acc[8] = {0.f, 0.f, 0.f, 0.f, 0.f, 0.f, 0.f, 0.f};

        for (int e = 0; e < ne; e += 16) {
            int i0 = e >> 2;                  // 0,4,8,12 -> pp4[i0..i0+3] in-bounds
            uint4 p0 = pp4[i0], p1 = pp4[i0 + 1], p2 = pp4[i0 + 2], p3 = pp4[i0 + 3];
            unsigned ua[16] = {p0.x, p0.y, p0.z, p0.w, p1.x, p1.y, p1.z, p1.w,
                               p2.x, p2.y, p2.z, p2.w, p3.x, p3.y, p3.z, p3.w};
            #pragma unroll
            for (int q = 0; q < 16; ++q)
                if (e + q >= ne) ua[q] = DUMMY;          // mask before address calc
            bf16x8 xv[16];
            #pragma unroll
            for (int q = 0; q < 16; ++q)
                xv[q] = *reinterpret_cast<const bf16x8*>(
                    xb + (size_t)(ua[q] & 0xFFFFu) * DIM + c0);
            #pragma unroll
            for (int q = 0; q < 16; ++q) {
                c0v += 1ull << (12 * ((ua[q] >> 16) & 7u));
                c1v += 1u   << (10 * (ua[q] >> 19));
            }
            #pragma unroll
            for (int j = 0; j < 8; ++j) {
                float sA0 = (bf2f(xv[0][j])  + bf2f(xv[1][j]))  + (bf2f(xv[2][j])  + bf2f(xv[3][j]));
                float sB0 = (bf2f(xv[4][j])  + bf2f(xv[5][j]))  + (bf2f(xv[6][j])  + bf2f(xv[7][j]));
                float sC0 = (bf2f(xv[8][j])  + bf2f(xv[9][j]))  + (bf2f(xv[10][j]) + bf2f(xv[11][j]));
                float sD0 = (bf2f(xv[12][j]) + bf2f(xv[13][j])) + (bf2f(xv[14][j]) + bf2f(xv[15][j]));
                acc[j] += (sA0 + sB0) + (sC0 + sD0);
            }
        }

        #pragma unroll
        for (int j = 0; j < 8; ++j) acc[j] += bf2f(sx[j]);

        #pragma unroll
        for (int tt = 0; tt < 5; ++tt) {
            float m = (float)((unsigned int)((c0v >> (12 * tt)) & 0xFFFu));
            const float* er = e1 + tt * DIM + c0;
            float4 u0 = *reinterpret_cast<const float4*>(er);
            float4 u1 = *reinterpret_cast<const float4*>(er + 4);
            acc[0] += m * u0.x; acc[1] += m * u0.y;
            acc[2] += m * u0.z; acc[3] += m * u0.w;
            acc[4] += m * u1.x; acc[5] += m * u1.y;
            acc[6] += m * u1.z; acc[7] += m * u1.w;
        }
        #pragma unroll
        for (int tt = 0; tt < 3; ++tt) {
            float m = (float)((c1v >> (10 * tt)) & 0x3FFu);
            const float* er = e2 + tt * DIM + c0;
            float4 u0 = *reinterpret_cast<const float4*>(er);
            float4 u1 = *reinterpret_cast<const float4*>(er + 4);
            acc[0] += m * u0.x; acc[1] += m * u0.y;
            acc[2] += m * u0.z; acc[3] += m * u0.w;
            acc[4] += m * u1.x; acc[5] += m * u1.y;
            acc[6] += m * u1.z; acc[7] += m * u1.w;
        }

        bf16x8 o;
        #pragma unroll
        for (int j = 0; j < 8; ++j) o[j] = (short)f2bf(acc[j]);
        *reinterpret_cast<bf16x8*>(&sA[n][c0]) = o;
    }
    __syncthreads();

    int wid = t >> 6;
    int l   = t & 63;
    int l16 = l & 15;
    int lhi = l >> 4;
    int rowbase = blockIdx.x * BLK_ROWS;

    // A fragments from LDS (reused across all stage-1 tiles)
    bf16x8 af[4];
    #pragma unroll
    for (int kk = 0; kk < 4; ++kk)
        af[kk] = *reinterpret_cast<const bf16x8*>(&sA[l16][kk * 32 + lhi * 8]);

    // ---------- stage 1: H = relu(A @ W1^T + b1); 4 tiles/wave, kk-outer ----------
    float tb1[4];
    #pragma unroll
    for (int i = 0; i < 4; ++i) tb1[i] = b1[(wid * 4 + i) * 16 + l16];

    f32x4 acc1[4];
    #pragma unroll
    for (int i = 0; i < 4; ++i) acc1[i] = (f32x4){0.f, 0.f, 0.f, 0.f};

    #pragma unroll
    for (int kk = 0; kk < 4; ++kk) {
        bf16x8 wf[4];
        #pragma unroll
        for (int i = 0; i < 4; ++i)
            wf[i] = *reinterpret_cast<const bf16x8*>(
                w1b + (size_t)((wid * 4 + i) * 16 + l16) * DIM + kk * 32 + lhi * 8);
        #pragma unroll
        for (int i = 0; i < 4; ++i)
            acc1[i] = __builtin_amdgcn_mfma_f32_16x16x32_bf16(af[kk], wf[i], acc1[i], 0, 0, 0);
    }
    #pragma unroll
    for (int i = 0; i < 4; ++i) {
        int n0 = (wid * 4 + i) * 16;
        #pragma unroll
        for (int r = 0; r < 4; ++r)
            sH[lhi * 4 + r][n0 + l16] = f2bf(fmaxf(acc1[i][r] + tb1[i], 0.f));
    }
    __syncthreads();

    // ---------- stage 2: Y = H @ W2^T + b2; 2 tiles/wave, kk-outer over K=256 ----------
    float tb2[2];
    #pragma unroll
    for (int i = 0; i < 2; ++i) tb2[i] = b2[(wid * 2 + i) * 16 + l16];

    f32x4 acc2[2];
    #pragma unroll
    for (int i = 0; i < 2; ++i) acc2[i] = (f32x4){0.f, 0.f, 0.f, 0.f};

    #pragma unroll
    for (int kk = 0; kk < 8; ++kk) {
        bf16x8 hf = *reinterpret_cast<const bf16x8*>(&sH[l16][kk * 32 + lhi * 8]);
        bf16x8 wf[2];
        #pragma unroll
        for (int i = 0; i < 2; ++i)
            wf[i] = *reinterpret_cast<const bf16x8*>(
                w2b + (size_t)((wid * 2 + i) * 16 + l16) * 256 + kk * 32 + lhi * 8);
        #pragma unroll
        for (int i = 0; i < 2; ++i)
            acc2[i] = __builtin_amdgcn_mfma_f32_16x16x32_bf16(hf, wf[i], acc2[i], 0, 0, 0);
    }
    #pragma unroll
    for (int i = 0; i < 2; ++i) {
        int n0 = (wid * 2 + i) * 16;
        #pragma unroll
        for (int r = 0; r < 4; ++r)
            Y[(size_t)(rowbase + lhi * 4 + r) * DIM + n0 + l16] = acc2[i][r] + tb2[i];
    }
}

extern "C" void kernel_launch(void* const* d_in, const int* in_sizes, int n_in,
                              void* d_out, int out_size, void* d_ws, size_t ws_size,
                              hipStream_t stream)
{
    const float* x   = (const float*)d_in[0];
    const int*  eidx = (const int*)d_in[1];
    const int*  eattr= (const int*)d_in[2];
    const float* W1  = (const float*)d_in[3];
    const float* b1  = (const float*)d_in[4];
    const float* W2  = (const float*)d_in[5];
    const float* b2  = (const float*)d_in[6];
    const float* e1  = (const float*)d_in[7];
    const float* e2  = (const float*)d_in[8];
    float* Y = (float*)d_out;

    char* ws = (char*)d_ws;
    int* cnt             = (int*)(ws + WS_CNT_OFF);
    unsigned int* perm   = (unsigned int*)(ws + WS_PERM_OFF);
    unsigned short* xb   = (unsigned short*)(ws + WS_XB_OFF);
    unsigned short* w1b  = (unsigned short*)(ws + WS_W1B_OFF);
    unsigned short* w2b  = (unsigned short*)(ws + WS_W2B_OFF);

    hipMemsetAsync(cnt, 0, N_NODES * sizeof(int), stream);
    prep_kernel     <<<PREP_GRID, 256, 0, stream>>>(
                        x, W1, W2, eidx, eattr, xb, w1b, w2b, cnt, perm);
    fused_mlp_kernel<<<GRID_FUSED, 256, 0, stream>>>(
                        xb, e1, e2, perm, cnt, w1b, b1, w2b, b2, Y);
}

// Round 13
// 116.890 us; speedup vs baseline: 1.0685x; 1.0685x over previous
//
#include <hip/hip_runtime.h>

#define N_NODES 50000
#define N_EDGES 600000
#define DIM 128

#define CAP 64                 // bucket capacity per node (deg ~Poisson(12))
#define GRID_E 2344            // ceil(600000/256), 1 edge/thread
#define BLK_ROWS 16
#define GRID_FUSED 3125        // 50000/16 exact

// dummy edge: col=zero-row(50000), a0=5 (bits 60+ of cnt0), a1=3 (bits 30+ of cnt1)
#define DUMMY (50000u | (5u << 16) | (3u << 19))

// ---- ws layout (bytes), 16B-aligned ----
#define WS_CNT_OFF   0          // cnt[50000] int
#define WS_PERM_OFF  200000     // perm[50000*64] u32 = 12.8 MB
#define WS_XB_OFF    13000000   // xb [50001*128] bf16 (row 50000 = zeros)
#define WS_W1B_OFF   25800256   // w1b [256*128] bf16
#define WS_W2B_OFF   25865792   // w2b [128*256] bf16
// total ~25.93 MB

#define CVT_X4    1600000       // 50000*128/4
#define CVT_XROWS 1600032       // + zero row
#define CVT_W4    8192          // 256*128/4
#define CVT_TOTAL (CVT_XROWS + 2 * CVT_W4)
#define CVT_BLOCKS ((CVT_TOTAL + 255) / 256)
#define ZERO_BLOCKS 196         // ceil(50000/256)

typedef __attribute__((ext_vector_type(8))) short bf16x8;
typedef __attribute__((ext_vector_type(4))) float f32x4;

__device__ __forceinline__ unsigned short f2bf(float f) {
    unsigned int b = __float_as_uint(f);
    b += 0x7FFFu + ((b >> 16) & 1u);     // round-to-nearest-even
    return (unsigned short)(b >> 16);
}
__device__ __forceinline__ float bf2f(short u) {
    return __uint_as_float(((unsigned int)(unsigned short)u) << 16);
}

// bucket placement, 1 edge/thread (max wave-parallelism for atomic chains):
// perm[row*CAP + pos] = col | a0<<16 | a1<<19
__global__ __launch_bounds__(256) void place_kernel(
    const int* __restrict__ eidx, const int* __restrict__ eattr,
    int* __restrict__ cnt, unsigned int* __restrict__ perm)
{
    int e = blockIdx.x * 256 + threadIdx.x;
    if (e >= N_EDGES) return;
    int row = eidx[e];
    unsigned int col = (unsigned int)eidx[N_EDGES + e];
    unsigned int a0  = (unsigned int)eattr[2 * e];
    unsigned int a1  = (unsigned int)eattr[2 * e + 1];
    int pos = atomicAdd(&cnt[row], 1);
    if (pos < CAP)
        perm[(size_t)row * CAP + pos] = col | (a0 << 16) | (a1 << 19);
}

// fused conversions (x->bf16 + zero row, W1->bf16, W2->bf16) + cnt zeroing
__global__ __launch_bounds__(256) void cvt_all_kernel(
    const float* __restrict__ x, const float* __restrict__ W1,
    const float* __restrict__ W2, unsigned short* __restrict__ xb,
    unsigned short* __restrict__ w1b, unsigned short* __restrict__ w2b,
    int* __restrict__ cnt)
{
    if (blockIdx.x >= CVT_BLOCKS) {
        int j = (blockIdx.x - CVT_BLOCKS) * 256 + threadIdx.x;
        if (j < N_NODES) cnt[j] = 0;
        return;
    }
    int i = blockIdx.x * 256 + threadIdx.x;
    if (i < CVT_X4) {
        float4 v = reinterpret_cast<const float4*>(x)[i];
        reinterpret_cast<ushort4*>(xb)[i] =
            make_ushort4(f2bf(v.x), f2bf(v.y), f2bf(v.z), f2bf(v.w));
    } else if (i < CVT_XROWS) {
        reinterpret_cast<ushort4*>(xb)[i] = make_ushort4(0, 0, 0, 0);
    } else if (i < CVT_XROWS + CVT_W4) {
        int j = i - CVT_XROWS;
        float4 v = reinterpret_cast<const float4*>(W1)[j];
        reinterpret_cast<ushort4*>(w1b)[j] =
            make_ushort4(f2bf(v.x), f2bf(v.y), f2bf(v.z), f2bf(v.w));
    } else if (i < CVT_TOTAL) {
        int j = i - CVT_XROWS - CVT_W4;
        float4 v = reinterpret_cast<const float4*>(W2)[j];
        reinterpret_cast<ushort4*>(w2b)[j] =
            make_ushort4(f2bf(v.x), f2bf(v.y), f2bf(v.z), f2bf(v.w));
    }
}

// Fused: gather 16 node rows into LDS (bf16), then MLP via MFMA.  (measured 81 µs)
//   agg = xb[g] + Σ_edges xb[col] + Σ_t cnt0[t]·e1[t] + Σ_t cnt1[t]·e2[t]
//   Y   = relu(agg @ W1^T + b1) @ W2^T + b2
// Self row read from xb (bf16, cache-hot): FETCH 99.6 -> 89.5 MB vs f32 x.
// Gather issues 16 UNCONDITIONAL loads per iteration (OOB -> DUMMY row).
// 16x16x32 frag: lane l -> row (l&15), k=(l>>4)*8+j ; D: row=(l>>4)*4+r, col=l&15.
__global__ __launch_bounds__(256, 4) void fused_mlp_kernel(
    const unsigned short* __restrict__ xb,
    const float* __restrict__ e1, const float* __restrict__ e2,
    const unsigned int* __restrict__ perm, const int* __restrict__ cnt,
    const unsigned short* __restrict__ w1b, const float* __restrict__ b1,
    const unsigned short* __restrict__ w2b, const float* __restrict__ b2,
    float* __restrict__ Y)
{
    __shared__ __align__(16) unsigned short sA[16][136];   // 4352 B
    __shared__ __align__(16) unsigned short sH[16][264];   // 8448 B

    int t = threadIdx.x;

    // ---------- gather: 16 lanes per node, 16-deep unconditional batches ----------
    {
        int n  = t >> 4;                      // row within block (grid exact)
        int g  = blockIdx.x * BLK_ROWS + n;
        int ln = t & 15, c0 = ln * 8;

        bf16x8 sx = *reinterpret_cast<const bf16x8*>(xb + (size_t)g * DIM + c0);

        int ne = cnt[g]; if (ne > CAP) ne = CAP;
        const uint4* pp4 = reinterpret_cast<const uint4*>(perm + (size_t)g * CAP);

        unsigned long long c0v = 1ull << 48;  // self-loop a0=4 (12*4)
        unsigned int       c1v = 1u;          // self-loop a1=0
        float acc[8] = {0.f, 0.f, 0.f, 0.f, 0.f, 0.f, 0.f, 0.f};

        for (int e = 0; e < ne; e += 16) {
            int i0 = e >> 2;                  // 0,4,8,12 -> pp4[i0..i0+3] in-bounds
            uint4 p0 = pp4[i0], p1 = pp4[i0 + 1], p2 = pp4[i0 + 2], p3 = pp4[i0 + 3];
            unsigned ua[16] = {p0.x, p0.y, p0.z, p0.w, p1.x, p1.y, p1.z, p1.w,
                               p2.x, p2.y, p2.z, p2.w, p3.x, p3.y, p3.z, p3.w};
            #pragma unroll
            for (int q = 0; q < 16; ++q)
                if (e + q >= ne) ua[q] = DUMMY;          // mask before address calc
            bf16x8 xv[16];
            #pragma unroll
            for (int q = 0; q < 16; ++q)
                xv[q] = *reinterpret_cast<const bf16x8*>(
                    xb + (size_t)(ua[q] & 0xFFFFu) * DIM + c0);
            #pragma unroll
            for (int q = 0; q < 16; ++q) {
                c0v += 1ull << (12 * ((ua[q] >> 16) & 7u));
                c1v += 1u   << (10 * (ua[q] >> 19));
            }
            #pragma unroll
            for (int j = 0; j < 8; ++j) {
                float sA0 = (bf2f(xv[0][j])  + bf2f(xv[1][j]))  + (bf2f(xv[2][j])  + bf2f(xv[3][j]));
                float sB0 = (bf2f(xv[4][j])  + bf2f(xv[5][j]))  + (bf2f(xv[6][j])  + bf2f(xv[7][j]));
                float sC0 = (bf2f(xv[8][j])  + bf2f(xv[9][j]))  + (bf2f(xv[10][j]) + bf2f(xv[11][j]));
                float sD0 = (bf2f(xv[12][j]) + bf2f(xv[13][j])) + (bf2f(xv[14][j]) + bf2f(xv[15][j]));
                acc[j] += (sA0 + sB0) + (sC0 + sD0);
            }
        }

        #pragma unroll
        for (int j = 0; j < 8; ++j) acc[j] += bf2f(sx[j]);

        #pragma unroll
        for (int tt = 0; tt < 5; ++tt) {
            float m = (float)((unsigned int)((c0v >> (12 * tt)) & 0xFFFu));
            const float* er = e1 + tt * DIM + c0;
            float4 u0 = *reinterpret_cast<const float4*>(er);
            float4 u1 = *reinterpret_cast<const float4*>(er + 4);
            acc[0] += m * u0.x; acc[1] += m * u0.y;
            acc[2] += m * u0.z; acc[3] += m * u0.w;
            acc[4] += m * u1.x; acc[5] += m * u1.y;
            acc[6] += m * u1.z; acc[7] += m * u1.w;
        }
        #pragma unroll
        for (int tt = 0; tt < 3; ++tt) {
            float m = (float)((c1v >> (10 * tt)) & 0x3FFu);
            const float* er = e2 + tt * DIM + c0;
            float4 u0 = *reinterpret_cast<const float4*>(er);
            float4 u1 = *reinterpret_cast<const float4*>(er + 4);
            acc[0] += m * u0.x; acc[1] += m * u0.y;
            acc[2] += m * u0.z; acc[3] += m * u0.w;
            acc[4] += m * u1.x; acc[5] += m * u1.y;
            acc[6] += m * u1.z; acc[7] += m * u1.w;
        }

        bf16x8 o;
        #pragma unroll
        for (int j = 0; j < 8; ++j) o[j] = (short)f2bf(acc[j]);
        *reinterpret_cast<bf16x8*>(&sA[n][c0]) = o;
    }
    __syncthreads();

    int wid = t >> 6;
    int l   = t & 63;
    int l16 = l & 15;
    int lhi = l >> 4;
    int rowbase = blockIdx.x * BLK_ROWS;

    // A fragments from LDS (reused across all stage-1 tiles)
    bf16x8 af[4];
    #pragma unroll
    for (int kk = 0; kk < 4; ++kk)
        af[kk] = *reinterpret_cast<const bf16x8*>(&sA[l16][kk * 32 + lhi * 8]);

    // ---------- stage 1: H = relu(A @ W1^T + b1); 4 tiles/wave, kk-outer ----------
    float tb1[4];
    #pragma unroll
    for (int i = 0; i < 4; ++i) tb1[i] = b1[(wid * 4 + i) * 16 + l16];

    f32x4 acc1[4];
    #pragma unroll
    for (int i = 0; i < 4; ++i) acc1[i] = (f32x4){0.f, 0.f, 0.f, 0.f};

    #pragma unroll
    for (int kk = 0; kk < 4; ++kk) {
        bf16x8 wf[4];
        #pragma unroll
        for (int i = 0; i < 4; ++i)
            wf[i] = *reinterpret_cast<const bf16x8*>(
                w1b + (size_t)((wid * 4 + i) * 16 + l16) * DIM + kk * 32 + lhi * 8);
        #pragma unroll
        for (int i = 0; i < 4; ++i)
            acc1[i] = __builtin_amdgcn_mfma_f32_16x16x32_bf16(af[kk], wf[i], acc1[i], 0, 0, 0);
    }
    #pragma unroll
    for (int i = 0; i < 4; ++i) {
        int n0 = (wid * 4 + i) * 16;
        #pragma unroll
        for (int r = 0; r < 4; ++r)
            sH[lhi * 4 + r][n0 + l16] = f2bf(fmaxf(acc1[i][r] + tb1[i], 0.f));
    }
    __syncthreads();

    // ---------- stage 2: Y = H @ W2^T + b2; 2 tiles/wave, kk-outer over K=256 ----------
    float tb2[2];
    #pragma unroll
    for (int i = 0; i < 2; ++i) tb2[i] = b2[(wid * 2 + i) * 16 + l16];

    f32x4 acc2[2];
    #pragma unroll
    for (int i = 0; i < 2; ++i) acc2[i] = (f32x4){0.f, 0.f, 0.f, 0.f};

    #pragma unroll
    for (int kk = 0; kk < 8; ++kk) {
        bf16x8 hf = *reinterpret_cast<const bf16x8*>(&sH[l16][kk * 32 + lhi * 8]);
        bf16x8 wf[2];
        #pragma unroll
        for (int i = 0; i < 2; ++i)
            wf[i] = *reinterpret_cast<const bf16x8*>(
                w2b + (size_t)((wid * 2 + i) * 16 + l16) * 256 + kk * 32 + lhi * 8);
        #pragma unroll
        for (int i = 0; i < 2; ++i)
            acc2[i] = __builtin_amdgcn_mfma_f32_16x16x32_bf16(hf, wf[i], acc2[i], 0, 0, 0);
    }
    #pragma unroll
    for (int i = 0; i < 2; ++i) {
        int n0 = (wid * 2 + i) * 16;
        #pragma unroll
        for (int r = 0; r < 4; ++r)
            Y[(size_t)(rowbase + lhi * 4 + r) * DIM + n0 + l16] = acc2[i][r] + tb2[i];
    }
}

extern "C" void kernel_launch(void* const* d_in, const int* in_sizes, int n_in,
                              void* d_out, int out_size, void* d_ws, size_t ws_size,
                              hipStream_t stream)
{
    const float* x   = (const float*)d_in[0];
    const int*  eidx = (const int*)d_in[1];
    const int*  eattr= (const int*)d_in[2];
    const float* W1  = (const float*)d_in[3];
    const float* b1  = (const float*)d_in[4];
    const float* W2  = (const float*)d_in[5];
    const float* b2  = (const float*)d_in[6];
    const float* e1  = (const float*)d_in[7];
    const float* e2  = (const float*)d_in[8];
    float* Y = (float*)d_out;

    char* ws = (char*)d_ws;
    int* cnt             = (int*)(ws + WS_CNT_OFF);
    unsigned int* perm   = (unsigned int*)(ws + WS_PERM_OFF);
    unsigned short* xb   = (unsigned short*)(ws + WS_XB_OFF);
    unsigned short* w1b  = (unsigned short*)(ws + WS_W1B_OFF);
    unsigned short* w2b  = (unsigned short*)(ws + WS_W2B_OFF);

    cvt_all_kernel  <<<CVT_BLOCKS + ZERO_BLOCKS, 256, 0, stream>>>(
                        x, W1, W2, xb, w1b, w2b, cnt);
    place_kernel    <<<GRID_E, 256, 0, stream>>>(eidx, eattr, cnt, perm);
    fused_mlp_kernel<<<GRID_FUSED, 256, 0, stream>>>(
                        xb, e1, e2, perm, cnt, w1b, b1, w2b, b2, Y);
}